// Round 2
// baseline (371.786 us; speedup 1.0000x reference)
//
#include <hip/hip_runtime.h>
#include <math.h>

#define NSEG   1024
#define DFEAT  128
#define EPS_F  1e-6f
#define NCHUNK 8192   // blocks for segment-sum; 8192/256 CUs = 32 waves/CU (1-wave blocks)

// ps = softplus(ps_raw), with the reference's Threshold(-50) quirk:
// sp >= 50 -> ps = -50 (never triggers for N(0,1) inputs, kept for exactness)
__device__ __forceinline__ float softplus_thr(float v) {
    float sp = log1pf(__expf(v));
    return (sp >= 50.0f) ? -50.0f : sp;
}

// One wave (64 lanes) per contiguous node chunk. Lane t owns feature pair
// (2t, 2t+1); both features sit in the same half of D so p is lane-constant.
// Register-accumulate within a segment run; atomicAdd to global s[] only at
// segment boundaries (batch is sorted -> ~1-2 flushes per block).
__global__ __launch_bounds__(64)
void segsum_kernel(const float* __restrict__ x,
                   const int*   __restrict__ batch,
                   const float* __restrict__ ps_raw,
                   float* __restrict__ s,      // (NSEG, DFEAT) accumulators
                   float* __restrict__ cnt,    // (NSEG) node counts
                   int n_nodes, int chunk)
{
    const int t = threadIdx.x;                  // 0..63
    const int start = blockIdx.x * chunk;
    if (start >= n_nodes) return;
    const int end = min(start + chunk, n_nodes);

    const float p = softplus_thr(ps_raw[(t < 32) ? 0 : 1]);

    const float2* __restrict__ x2 = (const float2*)x;   // row = 64 float2

    int   cur = batch[start];
    float accx = 0.0f, accy = 0.0f;
    int   run = 0;

    for (int n = start; n < end; ++n) {
        const int sg = batch[n];
        if (sg != cur) {
            atomicAdd(&s[(size_t)cur * DFEAT + 2 * t],     accx);
            atomicAdd(&s[(size_t)cur * DFEAT + 2 * t + 1], accy);
            if (t == 0) atomicAdd(&cnt[cur], (float)run);
            accx = 0.0f; accy = 0.0f; run = 0; cur = sg;
        }
        const float2 v = x2[(size_t)n * 64 + t];
        const float ax = fabsf(v.x) + EPS_F;
        const float ay = fabsf(v.y) + EPS_F;
        // xa^p == exp(p * log(xa)); identical math for both branches of the ref
        accx += __expf(p * __logf(ax));
        accy += __expf(p * __logf(ay));
        ++run;
    }
    atomicAdd(&s[(size_t)cur * DFEAT + 2 * t],     accx);
    atomicAdd(&s[(size_t)cur * DFEAT + 2 * t + 1], accy);
    if (t == 0) atomicAdd(&cnt[cur], (float)run);
}

// One block per graph b: finalize gnp[b][:] = s^(1/p) * n^(-qs0) into LDS,
// then each thread i computes out[b][i] = dot(gnp, W[i][:]) + bias[i].
// W is 64 KB -> fully L2-resident across the 1024 blocks.
__global__ __launch_bounds__(128)
void finalize_gemm_kernel(const float* __restrict__ s,
                          const float* __restrict__ cnt,
                          const float* __restrict__ ps_raw,
                          const float* __restrict__ qs_raw,
                          const float* __restrict__ W,
                          const float* __restrict__ bias,
                          float* __restrict__ out)
{
    __shared__ float g[DFEAT];
    const int b = blockIdx.x;
    const int i = threadIdx.x;                  // 0..127

    const float p  = softplus_thr(ps_raw[(i < 64) ? 0 : 1]);
    const float q0 = tanhf(qs_raw[0]);

    const float n     = cnt[b];
    const float scale = __expf(-q0 * __logf(n));        // n^(-qs0)
    const float sv    = s[(size_t)b * DFEAT + i];
    g[i] = __expf(__logf(sv) / p) * scale;              // s^(1/p) * n^(-qs0)
    __syncthreads();

    const float4* __restrict__ W4 = (const float4*)(W + (size_t)i * DFEAT);
    float acc = bias[i];
#pragma unroll
    for (int jj = 0; jj < DFEAT / 4; ++jj) {
        const float4 w = W4[jj];
        acc += g[4 * jj]     * w.x;
        acc += g[4 * jj + 1] * w.y;
        acc += g[4 * jj + 2] * w.z;
        acc += g[4 * jj + 3] * w.w;
    }
    out[(size_t)b * DFEAT + i] = acc;
}

extern "C" void kernel_launch(void* const* d_in, const int* in_sizes, int n_in,
                              void* d_out, int out_size, void* d_ws, size_t ws_size,
                              hipStream_t stream)
{
    const float* x      = (const float*)d_in[0];
    const int*   batch  = (const int*)  d_in[1];
    const float* ps_raw = (const float*)d_in[2];
    const float* qs_raw = (const float*)d_in[3];
    const float* W      = (const float*)d_in[4];
    const float* bias   = (const float*)d_in[5];
    float*       out    = (float*)d_out;

    const int n_nodes = in_sizes[0] / DFEAT;

    float* s   = (float*)d_ws;                 // NSEG*DFEAT floats
    float* cnt = s + (size_t)NSEG * DFEAT;     // NSEG floats

    // ws is re-poisoned to 0xAA before every call — zero the accumulators.
    hipMemsetAsync(d_ws, 0, sizeof(float) * ((size_t)NSEG * DFEAT + NSEG), stream);

    const int chunk = (n_nodes + NCHUNK - 1) / NCHUNK;   // ~62 nodes/block
    segsum_kernel<<<NCHUNK, 64, 0, stream>>>(x, batch, ps_raw, s, cnt, n_nodes, chunk);
    finalize_gemm_kernel<<<NSEG, 128, 0, stream>>>(s, cnt, ps_raw, qs_raw, W, bias, out);
}